// Round 3
// baseline (820.358 us; speedup 1.0000x reference)
//
#include <hip/hip_runtime.h>

typedef __attribute__((ext_vector_type(8))) __bf16 bf16x8;
typedef __attribute__((ext_vector_type(8))) short short8;
typedef __attribute__((ext_vector_type(4))) float f32x4;

#define CIN   256
#define HT    128
#define WD    128
#define TH    4            // tile height (output rows)
#define TWD   16           // tile width  (output cols)
#define TILES_PER_BLOCK 16
#define NBLK  256

// LDS layout:
//  xh: per-channel halo, 6 rows x 24 bf16 cols (cols x0-4 .. x0+19), stride 146
//  hb: h tile, 64 positions x 256 ch bf16, row stride 512B, XOR-swizzled
#define XH_STRIDE 146                    // ushort elems per channel region (73 dwords, odd -> bank spread)
#define HB_OFF    (CIN * XH_STRIDE * 2)  // 74752 bytes
#define LDS_BYTES (HB_OFF + 64 * 512)    // 107520 bytes

__device__ __forceinline__ unsigned short f2bf(float f) {
  unsigned u = __float_as_uint(f);
  u += 0x7FFFu + ((u >> 16) & 1u);       // round-to-nearest-even
  return (unsigned short)(u >> 16);
}

__global__ __launch_bounds__(256, 1) void fused_lbp_kernel(
    const float* __restrict__ x, const float* __restrict__ gamma,
    const float* __restrict__ beta, const float* __restrict__ rmean,
    const float* __restrict__ rvar, const float* __restrict__ lbp,
    const float* __restrict__ w1, const float* __restrict__ b1,
    float* __restrict__ out)
{
  extern __shared__ char lds[];
  unsigned short* xh = (unsigned short*)lds;
  char* hb = lds + HB_OFF;

  const int tid = threadIdx.x;
  const int wv  = tid >> 6;        // wave 0..3
  const int lr  = tid & 15;        // lane % 16
  const int lg  = (tid & 63) >> 4; // lane / 16 within wave

  // ---- per-block preload: w1 -> bf16 B-fragments (held in VGPRs), bias ----
  bf16x8 Breg[4][8];
  float biasf[4];
#pragma unroll
  for (int nb = 0; nb < 4; ++nb) {
    const int o = wv * 64 + nb * 16 + lr;
    biasf[nb] = b1[o];
#pragma unroll
    for (int kb = 0; kb < 8; ++kb) {
      const float* src = w1 + o * CIN + kb * 32 + lg * 8;
      f32x4 p0 = *(const f32x4*)(src);
      f32x4 p1 = *(const f32x4*)(src + 4);
      short8 t;
#pragma unroll
      for (int e = 0; e < 4; ++e) {
        t[e]     = (short)f2bf(p0[e]);
        t[e + 4] = (short)f2bf(p1[e]);
      }
      Breg[nb][kb] = __builtin_bit_cast(bf16x8, t);
    }
  }

  // ---- per-thread (== channel) conv constants ----
  const int c = tid;
  float w9[9];
#pragma unroll
  for (int k = 0; k < 9; ++k) w9[k] = lbp[c * 9 + k];
  const float aC = gamma[c] * rsqrtf(rvar[c] + 1e-5f);
  const float bC = beta[c] - rmean[c] * aC;
  // NOTE: reference zero-pads h = BN(x) before the depthwise conv, so
  // out-of-bounds taps contribute 0 -> the BN-shift term must use the
  // VALID-tap weight sum per pixel, not the all-9 sum (Round-2 border bug).

  // XCD-chunked remap: blocks on one XCD own adjacent tile chunks (L2 halo reuse)
  const int chunk = (blockIdx.x & 7) * 32 + (blockIdx.x >> 3);

  for (int i = 0; i < TILES_PER_BLOCK; ++i) {
    const int t  = chunk * TILES_PER_BLOCK + i;
    const int b  = t >> 8;
    const int ty = (t >> 3) & 31;
    const int tx = t & 7;
    const int y0 = ty * TH;
    const int x0 = tx * TWD;
    const float* xb = x + (size_t)b * CIN * HT * WD;

    // ---------- stage halo: x[b][:, y0-1..y0+4, x0-4..x0+19] -> xh (bf16) ----------
    // 256 ch x 6 rows x 6 float4 slots = 9216 slots, 36 per thread
    const bool interior = (ty >= 1) & (ty <= 30) & (tx >= 1) & (tx <= 6);
    if (interior) {
#pragma unroll
      for (int k = 0; k < 36; ++k) {
        int j  = k * 256 + tid;
        int cc = j / 36;
        int s  = j - cc * 36;
        int r  = s / 6;
        int p  = s - r * 6;
        const float* src = xb + ((cc * HT) + (y0 - 1 + r)) * WD + (x0 - 4 + p * 4);
        f32x4 v = *(const f32x4*)src;
        unsigned lo = (unsigned)f2bf(v[0]) | ((unsigned)f2bf(v[1]) << 16);
        unsigned hi = (unsigned)f2bf(v[2]) | ((unsigned)f2bf(v[3]) << 16);
        unsigned* dst = (unsigned*)(xh + cc * XH_STRIDE + r * 24 + p * 4);
        dst[0] = lo;
        dst[1] = hi;
      }
    } else {
#pragma unroll
      for (int k = 0; k < 36; ++k) {
        int j  = k * 256 + tid;
        int cc = j / 36;
        int s  = j - cc * 36;
        int r  = s / 6;
        int p  = s - r * 6;
        int gy  = y0 - 1 + r;
        int gx0 = x0 - 4 + p * 4;
        float v0 = 0.f, v1 = 0.f, v2 = 0.f, v3 = 0.f;
        if ((unsigned)gy < (unsigned)HT) {
          const float* rowp = xb + ((cc * HT) + gy) * WD;
          if ((unsigned)(gx0 + 0) < (unsigned)WD) v0 = rowp[gx0 + 0];
          if ((unsigned)(gx0 + 1) < (unsigned)WD) v1 = rowp[gx0 + 1];
          if ((unsigned)(gx0 + 2) < (unsigned)WD) v2 = rowp[gx0 + 2];
          if ((unsigned)(gx0 + 3) < (unsigned)WD) v3 = rowp[gx0 + 3];
        }
        unsigned lo = (unsigned)f2bf(v0) | ((unsigned)f2bf(v1) << 16);
        unsigned hi = (unsigned)f2bf(v2) | ((unsigned)f2bf(v3) << 16);
        unsigned* dst = (unsigned*)(xh + cc * XH_STRIDE + r * 24 + p * 4);
        dst[0] = lo;
        dst[1] = hi;
      }
    }
    __syncthreads();   // xh ready

    // ---------- depthwise 3x3 + BN + ReLU + residual -> hb (bf16, swizzled) ----------
    {
      const unsigned short* xr = xh + c * XH_STRIDE;
      // sliding window: Wa=col px+3, Wb=col px+4 (center), Wc=col px+5
      float Wa[6], Wb[6], Wc[6];
#pragma unroll
      for (int r = 0; r < 6; ++r) {
        Wa[r] = __uint_as_float((unsigned)xr[r * 24 + 3] << 16);
        Wb[r] = __uint_as_float((unsigned)xr[r * 24 + 4] << 16);
      }
#pragma unroll
      for (int px = 0; px < 16; ++px) {
#pragma unroll
        for (int r = 0; r < 6; ++r)
          Wc[r] = __uint_as_float((unsigned)xr[r * 24 + px + 5] << 16);

        // per-column tap validity (image borders): left/right neighbor cols
        const int gx = x0 + px;
        const float cl = (gx > 0)   ? 1.f : 0.f;
        const float cr = (gx < 127) ? 1.f : 0.f;
        const float t0 = fmaf(cl, w9[0], w9[1]) + cr * w9[2];
        const float t1 = fmaf(cl, w9[3], w9[4]) + cr * w9[5];
        const float t2 = fmaf(cl, w9[6], w9[7]) + cr * w9[8];

#pragma unroll
        for (int py = 0; py < 4; ++py) {
          float s;
          s = w9[0] * Wa[py];
          s = fmaf(w9[1], Wb[py],     s);
          s = fmaf(w9[2], Wc[py],     s);
          s = fmaf(w9[3], Wa[py + 1], s);
          s = fmaf(w9[4], Wb[py + 1], s);
          s = fmaf(w9[5], Wc[py + 1], s);
          s = fmaf(w9[6], Wa[py + 2], s);
          s = fmaf(w9[7], Wb[py + 2], s);
          s = fmaf(w9[8], Wc[py + 2], s);
          const int gy = y0 + py;
          float wsv = t1;
          wsv += (gy > 0)   ? t0 : 0.f;   // top row of taps valid?
          wsv += (gy < 127) ? t2 : 0.f;   // bottom row of taps valid?
          float hv = fmaxf(fmaf(aC, s, bC * wsv), 0.f) + Wb[py + 1]; // relu + residual x
          const int m = py * 16 + px;
          *(unsigned short*)(hb + m * 512 + ((2 * c) ^ ((m & 7) << 4))) = f2bf(hv);
        }
#pragma unroll
        for (int r = 0; r < 6; ++r) { Wa[r] = Wb[r]; Wb[r] = Wc[r]; }
      }
    }
    __syncthreads();   // hb ready; xh free for next tile

    // ---------- GEMM: out[m][o] = sum_c h[m][c] * w1[o][c] + b1[o] ----------
    {
      f32x4 acc[4][4];
#pragma unroll
      for (int mb = 0; mb < 4; ++mb)
#pragma unroll
        for (int nb = 0; nb < 4; ++nb)
          acc[mb][nb] = (f32x4){0.f, 0.f, 0.f, 0.f};

#pragma unroll
      for (int kb = 0; kb < 8; ++kb) {
        bf16x8 a[4];
#pragma unroll
        for (int mb = 0; mb < 4; ++mb) {
          const int m = mb * 16 + lr;
          const int off = (kb * 64 + lg * 16) ^ ((m & 7) << 4);
          a[mb] = *(const bf16x8*)(hb + m * 512 + off);
        }
#pragma unroll
        for (int mb = 0; mb < 4; ++mb)
#pragma unroll
          for (int nb = 0; nb < 4; ++nb)
            acc[mb][nb] = __builtin_amdgcn_mfma_f32_16x16x32_bf16(
                a[mb], Breg[nb][kb], acc[mb][nb], 0, 0, 0);
      }

#pragma unroll
      for (int mb = 0; mb < 4; ++mb) {
#pragma unroll
        for (int nb = 0; nb < 4; ++nb) {
          const int o = wv * 64 + nb * 16 + lr;
          f32x4 v = acc[mb][nb];
          v += biasf[nb];
          float* dst = out + (((size_t)(b * CIN + o) * HT) + (y0 + mb)) * WD + x0 + lg * 4;
          *(f32x4*)dst = v;
        }
      }
    }
    // no third barrier needed: next stage writes xh (conv reads done before 2nd
    // barrier), next conv writes hb only after next iteration's first barrier,
    // which also orders it after this tile's GEMM reads.
  }
}

extern "C" void kernel_launch(void* const* d_in, const int* in_sizes, int n_in,
                              void* d_out, int out_size, void* d_ws, size_t ws_size,
                              hipStream_t stream) {
  const float* x     = (const float*)d_in[0];
  const float* gamma = (const float*)d_in[1];
  const float* beta  = (const float*)d_in[2];
  const float* rmean = (const float*)d_in[3];
  const float* rvar  = (const float*)d_in[4];
  const float* lbp   = (const float*)d_in[5];
  const float* w1    = (const float*)d_in[6];
  const float* b1    = (const float*)d_in[7];
  float* out = (float*)d_out;

  // allow >64KB dynamic LDS (idempotent; host-side attribute, graph-capture safe)
  (void)hipFuncSetAttribute((const void*)fused_lbp_kernel,
                            hipFuncAttributeMaxDynamicSharedMemorySize, LDS_BYTES);

  fused_lbp_kernel<<<dim3(NBLK), dim3(256), LDS_BYTES, stream>>>(
      x, gamma, beta, rmean, rvar, lbp, w1, b1, out);
}